// Round 1
// baseline (788.250 us; speedup 1.0000x reference)
//
#include <hip/hip_runtime.h>

#define D 128
#define TWO_D 256
#define LDSR 264   // LDS row stride in bf16 units: 256 + 8 pad -> 2-way bank aliasing (free)

typedef __attribute__((ext_vector_type(4))) float f32x4;
typedef __attribute__((ext_vector_type(8))) short bf16x8;

static __device__ __forceinline__ unsigned short f2bf(float x) {
  union { float f; unsigned u; } v; v.f = x;
  unsigned r = (v.u + 0x7fffu + ((v.u >> 16) & 1u)) >> 16;  // RNE
  return (unsigned short)r;
}

// ---- weight prep: fp32 -> bf16 for both W matrices (each 128x256) ----
__global__ void prep_weights(const float* __restrict__ wmsg,
                             const float* __restrict__ wapp,
                             unsigned short* __restrict__ wmsg_bf,
                             unsigned short* __restrict__ wapp_bf) {
  int i = blockIdx.x * blockDim.x + threadIdx.x;
  if (i < D * TWO_D) {
    wmsg_bf[i] = f2bf(wmsg[i]);
  } else {
    int j = i - D * TWO_D;
    if (j < D * TWO_D) wapp_bf[j] = f2bf(wapp[j]);
  }
}

// ---- CSR build: histogram by dst ----
__global__ void hist_kernel(const int* __restrict__ dst, int* __restrict__ counts,
                            int n_edges) {
  int e = blockIdx.x * blockDim.x + threadIdx.x;
  if (e < n_edges) atomicAdd(&counts[dst[e]], 1);
}

// ---- CSR build: single-block exclusive scan (N=50000) ----
__global__ void scan_kernel(const int* __restrict__ counts, int* __restrict__ offsets,
                            int* __restrict__ cursor, int n, int n_edges) {
  __shared__ int lds[1024];
  int t = threadIdx.x;
  int C = (n + 1023) / 1024;
  int beg = t * C;
  int end = beg + C; if (end > n) end = n;
  int s = 0;
  for (int i = beg; i < end; ++i) s += counts[i];
  lds[t] = s;
  __syncthreads();
  for (int off = 1; off < 1024; off <<= 1) {
    int v = (t >= off) ? lds[t - off] : 0;
    __syncthreads();
    lds[t] += v;
    __syncthreads();
  }
  int run = (t == 0) ? 0 : lds[t - 1];
  for (int i = beg; i < end; ++i) {
    offsets[i] = run;
    cursor[i] = run;
    run += counts[i];
  }
  if (t == 1023) offsets[n] = n_edges;
}

// ---- CSR build: scatter edge ids into per-dst buckets ----
__global__ void scatter_kernel(const int* __restrict__ dst, int* __restrict__ cursor,
                               int* __restrict__ edge_list, int n_edges) {
  int e = blockIdx.x * blockDim.x + threadIdx.x;
  if (e < n_edges) {
    int p = atomicAdd(&cursor[dst[e]], 1);
    edge_list[p] = e;
  }
}

// ---- gather: one wave per node; accumulate mean(concat(nfeats[src], efeats)) -> bf16 X1 ----
__global__ __launch_bounds__(256) void gather_kernel(
    const float* __restrict__ nfeats, const float* __restrict__ efeats,
    const int* __restrict__ src, const int* __restrict__ edge_list,
    const int* __restrict__ offsets, unsigned short* __restrict__ X1,
    int n_nodes) {
  int w = (blockIdx.x * 256 + threadIdx.x) >> 6;
  int lane = threadIdx.x & 63;
  if (w >= n_nodes) return;
  int beg = offsets[w], end = offsets[w + 1];
  const float2* nf = (const float2*)nfeats;
  const float2* ef = (const float2*)efeats;
  float s0 = 0.f, s1 = 0.f, e0 = 0.f, e1 = 0.f;
  for (int j = beg; j < end; ++j) {
    int e = edge_list[j];
    int s = src[e];
    float2 a = nf[s * 64 + lane];                 // 64 lanes -> 512B coalesced row
    float2 b = ef[(size_t)e * 64 + lane];
    s0 += a.x; s1 += a.y; e0 += b.x; e1 += b.y;
  }
  float inv = (end > beg) ? 1.0f / (float)(end - beg) : 0.0f;
  ushort2* Xv = (ushort2*)(X1 + (size_t)w * TWO_D);
  Xv[lane]      = make_ushort2(f2bf(s0 * inv), f2bf(s1 * inv));
  Xv[64 + lane] = make_ushort2(f2bf(e0 * inv), f2bf(e1 * inv));
}

// ---- node kernel: h = X1 @ Wmsg^T + b1*(cnt>0); out = relu(concat(nf,h) @ Wapp^T + b2) ----
// Block: 256 threads (4 waves), 64-node tile, MFMA 16x16x32 bf16.
__global__ __launch_bounds__(256) void node_gemm(
    const unsigned short* __restrict__ X1,
    const unsigned short* __restrict__ Wmsg,
    const unsigned short* __restrict__ Wapp,
    const float* __restrict__ b1,
    const float* __restrict__ b2,
    const float* __restrict__ nfeats,
    const int* __restrict__ offsets,
    float* __restrict__ out,
    int n_nodes) {
  __shared__ unsigned short xt[64 * LDSR];
  __shared__ int cnts[64];
  const int tid = threadIdx.x;
  const int base = blockIdx.x * 64;

  if (tid < 64) {
    int g = base + tid;
    cnts[tid] = (g < n_nodes) ? (offsets[g + 1] - offsets[g]) : 0;
  }
  // stage X1 tile (64 x 256 bf16) into LDS
  #pragma unroll
  for (int it = 0; it < 8; ++it) {
    int chunk = tid + it * 256;          // 2048 chunks of 8 bf16 (16B)
    int r = chunk >> 5, c = chunk & 31;
    int g = base + r;
    uint4 v = make_uint4(0, 0, 0, 0);
    if (g < n_nodes) v = ((const uint4*)X1)[(size_t)g * 32 + c];
    *(uint4*)&xt[r * LDSR + c * 8] = v;
  }
  __syncthreads();

  const int lane = tid & 63;
  const int wid = tid >> 6;
  const int m16 = lane & 15;
  const int quad = lane >> 4;
  const int arow = wid * 16 + m16;

  f32x4 acc[8];
  #pragma unroll
  for (int ot = 0; ot < 8; ++ot) acc[ot] = (f32x4){0.f, 0.f, 0.f, 0.f};

  // GEMM1: h = X1 @ Wmsg^T   (A[m][k]=X1 row, B-frag lane j holds Wmsg[o][k]=B^T row)
  #pragma unroll
  for (int k0 = 0; k0 < 256; k0 += 32) {
    bf16x8 a = *(const bf16x8*)&xt[arow * LDSR + k0 + quad * 8];
    #pragma unroll
    for (int ot = 0; ot < 8; ++ot) {
      int o = ot * 16 + m16;
      bf16x8 b = *(const bf16x8*)&Wmsg[o * 256 + k0 + quad * 8];
      acc[ot] = __builtin_amdgcn_mfma_f32_16x16x32_bf16(a, b, acc[ot], 0, 0, 0);
    }
  }
  __syncthreads();  // all waves done reading xt before overwrite

  // write h_neigh (bf16) into xt[:,128:256]; D layout: col=lane&15, row=quad*4+reg
  #pragma unroll
  for (int ot = 0; ot < 8; ++ot) {
    int o = ot * 16 + m16;
    float bias = b1[o];
    #pragma unroll
    for (int r = 0; r < 4; ++r) {
      int m = wid * 16 + quad * 4 + r;
      float h = acc[ot][r] + (cnts[m] > 0 ? bias : 0.0f);
      xt[m * LDSR + 128 + o] = f2bf(h);
    }
  }
  // stage nfeats (bf16) into xt[:,0:128]
  #pragma unroll
  for (int it = 0; it < 8; ++it) {
    int chunk = tid + it * 256;          // 2048 chunks of 4 floats
    int r = chunk >> 5, c = chunk & 31;
    int g = base + r;
    float4 v = make_float4(0.f, 0.f, 0.f, 0.f);
    if (g < n_nodes) v = ((const float4*)nfeats)[(size_t)g * 32 + c];
    ushort4 bv;
    bv.x = f2bf(v.x); bv.y = f2bf(v.y); bv.z = f2bf(v.z); bv.w = f2bf(v.w);
    *(ushort4*)&xt[r * LDSR + c * 4] = bv;
  }
  __syncthreads();

  #pragma unroll
  for (int ot = 0; ot < 8; ++ot) acc[ot] = (f32x4){0.f, 0.f, 0.f, 0.f};

  // GEMM2: out = relu(X2 @ Wapp^T + b2)
  #pragma unroll
  for (int k0 = 0; k0 < 256; k0 += 32) {
    bf16x8 a = *(const bf16x8*)&xt[arow * LDSR + k0 + quad * 8];
    #pragma unroll
    for (int ot = 0; ot < 8; ++ot) {
      int o = ot * 16 + m16;
      bf16x8 b = *(const bf16x8*)&Wapp[o * 256 + k0 + quad * 8];
      acc[ot] = __builtin_amdgcn_mfma_f32_16x16x32_bf16(a, b, acc[ot], 0, 0, 0);
    }
  }
  #pragma unroll
  for (int ot = 0; ot < 8; ++ot) {
    int o = ot * 16 + m16;
    float bias = b2[o];
    #pragma unroll
    for (int r = 0; r < 4; ++r) {
      int m = wid * 16 + quad * 4 + r;
      int g = base + m;
      if (g < n_nodes) {
        float v = acc[ot][r] + bias;
        out[(size_t)g * D + o] = v > 0.f ? v : 0.f;
      }
    }
  }
}

extern "C" void kernel_launch(void* const* d_in, const int* in_sizes, int n_in,
                              void* d_out, int out_size, void* d_ws, size_t ws_size,
                              hipStream_t stream) {
  const float* nfeats = (const float*)d_in[0];
  const float* efeats = (const float*)d_in[1];
  const float* Wmsg_f = (const float*)d_in[2];
  const float* b1     = (const float*)d_in[3];
  const float* Wapp_f = (const float*)d_in[4];
  const float* b2     = (const float*)d_in[5];
  const int*   src    = (const int*)d_in[6];
  const int*   dst    = (const int*)d_in[7];
  const int n_nodes = in_sizes[0] / D;
  const int n_edges = in_sizes[6];

  // workspace layout (~28.8 MB)
  char* ws = (char*)d_ws;
  size_t off = 0;
  unsigned short* X1 = (unsigned short*)(ws + off); off += (size_t)n_nodes * TWO_D * 2;
  unsigned short* wmsg_bf = (unsigned short*)(ws + off); off += (size_t)D * TWO_D * 2;
  unsigned short* wapp_bf = (unsigned short*)(ws + off); off += (size_t)D * TWO_D * 2;
  int* counts    = (int*)(ws + off); off += (size_t)n_nodes * 4;
  int* offsets   = (int*)(ws + off); off += (size_t)(n_nodes + 1) * 4;
  int* cursor    = (int*)(ws + off); off += (size_t)n_nodes * 4;
  int* edge_list = (int*)(ws + off); off += (size_t)n_edges * 4;
  (void)ws_size; (void)n_in; (void)out_size;

  hipMemsetAsync(counts, 0, (size_t)n_nodes * 4, stream);
  prep_weights<<<(2 * D * TWO_D + 255) / 256, 256, 0, stream>>>(Wmsg_f, Wapp_f, wmsg_bf, wapp_bf);
  hist_kernel<<<(n_edges + 255) / 256, 256, 0, stream>>>(dst, counts, n_edges);
  scan_kernel<<<1, 1024, 0, stream>>>(counts, offsets, cursor, n_nodes, n_edges);
  scatter_kernel<<<(n_edges + 255) / 256, 256, 0, stream>>>(dst, cursor, edge_list, n_edges);
  gather_kernel<<<(n_nodes + 3) / 4, 256, 0, stream>>>(nfeats, efeats, src, edge_list, offsets, X1, n_nodes);
  node_gemm<<<(n_nodes + 63) / 64, 256, 0, stream>>>(X1, wmsg_bf, wapp_bf, b1, b2, nfeats, offsets, (float*)d_out, n_nodes);
}

// Round 3
// 729.109 us; speedup vs baseline: 1.0811x; 1.0811x over previous
//
#include <hip/hip_runtime.h>

#define D 128
#define TWO_D 256
#define LDSR 264   // LDS row stride in bf16 units: 256 + 8 pad -> 2-way bank aliasing (free)

typedef __attribute__((ext_vector_type(4))) float f32x4;
typedef __attribute__((ext_vector_type(8))) short bf16x8;

static __device__ __forceinline__ unsigned short f2bf(float x) {
  union { float f; unsigned u; } v; v.f = x;
  unsigned r = (v.u + 0x7fffu + ((v.u >> 16) & 1u)) >> 16;  // RNE
  return (unsigned short)r;
}

// ---- weight prep (fp32 -> bf16, both 128x256) fused with counts zeroing ----
__global__ void prep_weights(const float* __restrict__ wmsg,
                             const float* __restrict__ wapp,
                             unsigned short* __restrict__ wmsg_bf,
                             unsigned short* __restrict__ wapp_bf,
                             int* __restrict__ counts, int n_nodes) {
  int i = blockIdx.x * blockDim.x + threadIdx.x;
  if (i < D * TWO_D) {
    wmsg_bf[i] = f2bf(wmsg[i]);
  } else if (i < 2 * D * TWO_D) {
    int j = i - D * TWO_D;
    wapp_bf[j] = f2bf(wapp[j]);
  }
  if (i < n_nodes) counts[i] = 0;   // 65536 threads >= 50000
}

// ---- CSR build: histogram by dst ----
__global__ void hist_kernel(const int* __restrict__ dst, int* __restrict__ counts,
                            int n_edges) {
  int e = blockIdx.x * blockDim.x + threadIdx.x;
  if (e < n_edges) atomicAdd(&counts[dst[e]], 1);
}

// ---- CSR build: single-block exclusive scan (N=50000) ----
__global__ void scan_kernel(const int* __restrict__ counts, int* __restrict__ offsets,
                            int* __restrict__ cursor, int n, int n_edges) {
  __shared__ int lds[1024];
  int t = threadIdx.x;
  int C = (n + 1023) / 1024;
  int beg = t * C;
  int end = beg + C; if (end > n) end = n;
  int s = 0;
  for (int i = beg; i < end; ++i) s += counts[i];
  lds[t] = s;
  __syncthreads();
  for (int off = 1; off < 1024; off <<= 1) {
    int v = (t >= off) ? lds[t - off] : 0;
    __syncthreads();
    lds[t] += v;
    __syncthreads();
  }
  int run = (t == 0) ? 0 : lds[t - 1];
  for (int i = beg; i < end; ++i) {
    offsets[i] = run;
    cursor[i] = run;
    run += counts[i];
  }
  if (t == 1023) offsets[n] = n_edges;
}

// ---- CSR build: scatter edge ids into per-dst buckets ----
__global__ void scatter_kernel(const int* __restrict__ dst, int* __restrict__ cursor,
                               int* __restrict__ edge_list, int n_edges) {
  int e = blockIdx.x * blockDim.x + threadIdx.x;
  if (e < n_edges) {
    int p = atomicAdd(&cursor[dst[e]], 1);
    edge_list[p] = e;
  }
}

// ---- gather v2: one wave per node. Phase 1: lanes batch-load edge ids + src ids
// (no per-iteration dependent chain). Phase 2: 2 edges per iteration, 32 lanes x
// float4 per row; all addresses known upfront -> deep MLP. efeats read-once ->
// nontemporal to preserve L2/L3 for nfeats.
__global__ __launch_bounds__(256) void gather_kernel(
    const float* __restrict__ nfeats, const float* __restrict__ efeats,
    const int* __restrict__ src, const int* __restrict__ edge_list,
    const int* __restrict__ offsets, unsigned short* __restrict__ X1,
    int n_nodes) {
  int w = (blockIdx.x * 256 + threadIdx.x) >> 6;
  int lane = threadIdx.x & 63;
  if (w >= n_nodes) return;
  int beg = offsets[w], end = offsets[w + 1];
  int cnt = end - beg;
  const f32x4* nf4 = (const f32x4*)nfeats;   // 32 f32x4 per row
  const f32x4* ef4 = (const f32x4*)efeats;
  const int c32 = lane & 31;    // column group: cols [c32*4 .. c32*4+3]
  const int slot = lane >> 5;   // which edge of the pair this half-wave handles
  f32x4 accn = (f32x4){0.f, 0.f, 0.f, 0.f};
  f32x4 acce = (f32x4){0.f, 0.f, 0.f, 0.f};

  for (int j0 = beg; j0 < end; j0 += 64) {
    int nj = end - j0; if (nj > 64) nj = 64;
    int e = 0, s = 0;
    if (lane < nj) { e = edge_list[j0 + lane]; s = src[e]; }
    #pragma unroll 2
    for (int p = 0; p < nj; p += 2) {
      int idx = p + slot;
      int ee = __shfl(e, idx);
      int ss = __shfl(s, idx);
      if (idx < nj) {
        f32x4 a = nf4[(size_t)ss * 32 + c32];
        f32x4 b = __builtin_nontemporal_load(&ef4[(size_t)ee * 32 + c32]);
        accn += a; acce += b;
      }
    }
  }
  // fold the two half-wave partials: all lanes end with full sums of both parts
  #pragma unroll
  for (int k = 0; k < 4; ++k) {
    accn[k] += __shfl_xor(accn[k], 32);
    acce[k] += __shfl_xor(acce[k], 32);
  }
  float inv = (cnt > 0) ? 1.0f / (float)cnt : 0.0f;
  f32x4 v = (lane < 32) ? accn : acce;   // lanes 0-31: nf half; 32-63: ef half
  ushort4 o;
  o.x = f2bf(v[0] * inv); o.y = f2bf(v[1] * inv);
  o.z = f2bf(v[2] * inv); o.w = f2bf(v[3] * inv);
  ((ushort4*)(X1 + (size_t)w * TWO_D))[lane] = o;  // elem offset = lane*4 (both halves)
}

// ---- node kernel: h = X1 @ Wmsg^T + b1*(cnt>0); out = relu(concat(nf,h) @ Wapp^T + b2) ----
__global__ __launch_bounds__(256) void node_gemm(
    const unsigned short* __restrict__ X1,
    const unsigned short* __restrict__ Wmsg,
    const unsigned short* __restrict__ Wapp,
    const float* __restrict__ b1,
    const float* __restrict__ b2,
    const float* __restrict__ nfeats,
    const int* __restrict__ offsets,
    float* __restrict__ out,
    int n_nodes) {
  __shared__ unsigned short xt[64 * LDSR];
  __shared__ int cnts[64];
  const int tid = threadIdx.x;
  const int base = blockIdx.x * 64;

  if (tid < 64) {
    int g = base + tid;
    cnts[tid] = (g < n_nodes) ? (offsets[g + 1] - offsets[g]) : 0;
  }
  // stage X1 tile (64 x 256 bf16) into LDS
  #pragma unroll
  for (int it = 0; it < 8; ++it) {
    int chunk = tid + it * 256;          // 2048 chunks of 8 bf16 (16B)
    int r = chunk >> 5, c = chunk & 31;
    int g = base + r;
    uint4 v = make_uint4(0, 0, 0, 0);
    if (g < n_nodes) v = ((const uint4*)X1)[(size_t)g * 32 + c];
    *(uint4*)&xt[r * LDSR + c * 8] = v;
  }
  __syncthreads();

  const int lane = tid & 63;
  const int wid = tid >> 6;
  const int m16 = lane & 15;
  const int quad = lane >> 4;
  const int arow = wid * 16 + m16;

  f32x4 acc[8];
  #pragma unroll
  for (int ot = 0; ot < 8; ++ot) acc[ot] = (f32x4){0.f, 0.f, 0.f, 0.f};

  // GEMM1: h = X1 @ Wmsg^T
  #pragma unroll
  for (int k0 = 0; k0 < 256; k0 += 32) {
    bf16x8 a = *(const bf16x8*)&xt[arow * LDSR + k0 + quad * 8];
    #pragma unroll
    for (int ot = 0; ot < 8; ++ot) {
      int o = ot * 16 + m16;
      bf16x8 b = *(const bf16x8*)&Wmsg[o * 256 + k0 + quad * 8];
      acc[ot] = __builtin_amdgcn_mfma_f32_16x16x32_bf16(a, b, acc[ot], 0, 0, 0);
    }
  }
  __syncthreads();  // all waves done reading xt before overwrite

  // write h_neigh (bf16) into xt[:,128:256]; D layout: col=lane&15, row=quad*4+reg
  #pragma unroll
  for (int ot = 0; ot < 8; ++ot) {
    int o = ot * 16 + m16;
    float bias = b1[o];
    #pragma unroll
    for (int r = 0; r < 4; ++r) {
      int m = wid * 16 + quad * 4 + r;
      float h = acc[ot][r] + (cnts[m] > 0 ? bias : 0.0f);
      xt[m * LDSR + 128 + o] = f2bf(h);
    }
  }
  // stage nfeats (bf16) into xt[:,0:128]
  #pragma unroll
  for (int it = 0; it < 8; ++it) {
    int chunk = tid + it * 256;          // 2048 chunks of 4 floats
    int r = chunk >> 5, c = chunk & 31;
    int g = base + r;
    float4 v = make_float4(0.f, 0.f, 0.f, 0.f);
    if (g < n_nodes) v = ((const float4*)nfeats)[(size_t)g * 32 + c];
    ushort4 bv;
    bv.x = f2bf(v.x); bv.y = f2bf(v.y); bv.z = f2bf(v.z); bv.w = f2bf(v.w);
    *(ushort4*)&xt[r * LDSR + c * 4] = bv;
  }
  __syncthreads();

  #pragma unroll
  for (int ot = 0; ot < 8; ++ot) acc[ot] = (f32x4){0.f, 0.f, 0.f, 0.f};

  // GEMM2: out = relu(X2 @ Wapp^T + b2)
  #pragma unroll
  for (int k0 = 0; k0 < 256; k0 += 32) {
    bf16x8 a = *(const bf16x8*)&xt[arow * LDSR + k0 + quad * 8];
    #pragma unroll
    for (int ot = 0; ot < 8; ++ot) {
      int o = ot * 16 + m16;
      bf16x8 b = *(const bf16x8*)&Wapp[o * 256 + k0 + quad * 8];
      acc[ot] = __builtin_amdgcn_mfma_f32_16x16x32_bf16(a, b, acc[ot], 0, 0, 0);
    }
  }
  #pragma unroll
  for (int ot = 0; ot < 8; ++ot) {
    int o = ot * 16 + m16;
    float bias = b2[o];
    #pragma unroll
    for (int r = 0; r < 4; ++r) {
      int m = wid * 16 + quad * 4 + r;
      int g = base + m;
      if (g < n_nodes) {
        float v = acc[ot][r] + bias;
        out[(size_t)g * D + o] = v > 0.f ? v : 0.f;
      }
    }
  }
}

extern "C" void kernel_launch(void* const* d_in, const int* in_sizes, int n_in,
                              void* d_out, int out_size, void* d_ws, size_t ws_size,
                              hipStream_t stream) {
  const float* nfeats = (const float*)d_in[0];
  const float* efeats = (const float*)d_in[1];
  const float* Wmsg_f = (const float*)d_in[2];
  const float* b1     = (const float*)d_in[3];
  const float* Wapp_f = (const float*)d_in[4];
  const float* b2     = (const float*)d_in[5];
  const int*   src    = (const int*)d_in[6];
  const int*   dst    = (const int*)d_in[7];
  const int n_nodes = in_sizes[0] / D;
  const int n_edges = in_sizes[6];

  // workspace layout (~28.8 MB)
  char* ws = (char*)d_ws;
  size_t off = 0;
  unsigned short* X1 = (unsigned short*)(ws + off); off += (size_t)n_nodes * TWO_D * 2;
  unsigned short* wmsg_bf = (unsigned short*)(ws + off); off += (size_t)D * TWO_D * 2;
  unsigned short* wapp_bf = (unsigned short*)(ws + off); off += (size_t)D * TWO_D * 2;
  int* counts    = (int*)(ws + off); off += (size_t)n_nodes * 4;
  int* offsets   = (int*)(ws + off); off += (size_t)(n_nodes + 1) * 4;
  int* cursor    = (int*)(ws + off); off += (size_t)n_nodes * 4;
  int* edge_list = (int*)(ws + off); off += (size_t)n_edges * 4;
  (void)ws_size; (void)n_in; (void)out_size;

  prep_weights<<<256, 256, 0, stream>>>(Wmsg_f, Wapp_f, wmsg_bf, wapp_bf, counts, n_nodes);
  hist_kernel<<<(n_edges + 255) / 256, 256, 0, stream>>>(dst, counts, n_edges);
  scan_kernel<<<1, 1024, 0, stream>>>(counts, offsets, cursor, n_nodes, n_edges);
  scatter_kernel<<<(n_edges + 255) / 256, 256, 0, stream>>>(dst, cursor, edge_list, n_edges);
  gather_kernel<<<(n_nodes + 3) / 4, 256, 0, stream>>>(nfeats, efeats, src, edge_list, offsets, X1, n_nodes);
  node_gemm<<<(n_nodes + 63) / 64, 256, 0, stream>>>(X1, wmsg_bf, wapp_bf, b1, b2, nfeats, offsets, (float*)d_out, n_nodes);
}

// Round 4
// 689.358 us; speedup vs baseline: 1.1435x; 1.0577x over previous
//
#include <hip/hip_runtime.h>

#define D 128
#define TWO_D 256
#define LDSR 264   // LDS row stride in bf16 units: 256 + 8 pad -> 2-way bank aliasing (free)

typedef __attribute__((ext_vector_type(4))) float f32x4;
typedef __attribute__((ext_vector_type(8))) short bf16x8;

static __device__ __forceinline__ unsigned short f2bf(float x) {
  union { float f; unsigned u; } v; v.f = x;
  unsigned r = (v.u + 0x7fffu + ((v.u >> 16) & 1u)) >> 16;  // RNE
  return (unsigned short)r;
}

// ---- prep: pack both weight matrices into MFMA-B-fragment order (bf16) so that
// node_gemm's B loads are fully coalesced: Wp[((g*8+k0i)*8+ot)*512 + lane*8 + j]
// holds W_g[o=ot*16+(lane&15)][k = k0i*32 + (lane>>4)*8 + j]. Also zeroes counts.
__global__ void prep_pack(const float* __restrict__ wmsg,
                          const float* __restrict__ wapp,
                          unsigned short* __restrict__ Wp,
                          int* __restrict__ counts, int n_nodes) {
  int p = blockIdx.x * blockDim.x + threadIdx.x;   // 65536 threads
  int j = p & 7;
  int lane = (p >> 3) & 63;
  int ot = (p >> 9) & 7;
  int k0i = (p >> 12) & 7;
  int g = p >> 15;
  int o = ot * 16 + (lane & 15);
  int k = k0i * 32 + (lane >> 4) * 8 + j;
  const float* W = g ? wapp : wmsg;
  Wp[p] = f2bf(W[o * 256 + k]);
  if (p < n_nodes) counts[p] = 0;
}

// ---- CSR build: histogram by dst ----
__global__ void hist_kernel(const int* __restrict__ dst, int* __restrict__ counts,
                            int n_edges) {
  int e = blockIdx.x * blockDim.x + threadIdx.x;
  if (e < n_edges) atomicAdd(&counts[dst[e]], 1);
}

// ---- CSR build: single-block exclusive scan (N=50000) ----
__global__ void scan_kernel(const int* __restrict__ counts, int* __restrict__ offsets,
                            int* __restrict__ cursor, int n, int n_edges) {
  __shared__ int lds[1024];
  int t = threadIdx.x;
  int C = (n + 1023) / 1024;
  int beg = t * C;
  int end = beg + C; if (end > n) end = n;
  int s = 0;
  for (int i = beg; i < end; ++i) s += counts[i];
  lds[t] = s;
  __syncthreads();
  for (int off = 1; off < 1024; off <<= 1) {
    int v = (t >= off) ? lds[t - off] : 0;
    __syncthreads();
    lds[t] += v;
    __syncthreads();
  }
  int run = (t == 0) ? 0 : lds[t - 1];
  for (int i = beg; i < end; ++i) {
    offsets[i] = run;
    cursor[i] = run;
    run += counts[i];
  }
  if (t == 1023) offsets[n] = n_edges;
}

// ---- CSR build: scatter edge ids into per-dst buckets ----
__global__ void scatter_kernel(const int* __restrict__ dst, int* __restrict__ cursor,
                               int* __restrict__ edge_list, int n_edges) {
  int e = blockIdx.x * blockDim.x + threadIdx.x;
  if (e < n_edges) {
    int p = atomicAdd(&cursor[dst[e]], 1);
    edge_list[p] = e;
  }
}

// ---- gather v3: one wave per node; batch edge/src ids; 4 edges in flight per
// iteration (2 pairs x 32 lanes x float4 = 512B coalesced rows). ----
__global__ __launch_bounds__(256) void gather_kernel(
    const float* __restrict__ nfeats, const float* __restrict__ efeats,
    const int* __restrict__ src, const int* __restrict__ edge_list,
    const int* __restrict__ offsets, unsigned short* __restrict__ X1,
    int n_nodes) {
  int w = (blockIdx.x * 256 + threadIdx.x) >> 6;
  int lane = threadIdx.x & 63;
  if (w >= n_nodes) return;
  int beg = offsets[w], end = offsets[w + 1];
  int cnt = end - beg;
  const f32x4* nf4 = (const f32x4*)nfeats;   // 32 f32x4 per row
  const f32x4* ef4 = (const f32x4*)efeats;
  const int c32 = lane & 31;    // column group: cols [c32*4 .. c32*4+3]
  const int slot = lane >> 5;   // which edge of a pair this half-wave handles
  f32x4 accn = (f32x4){0.f, 0.f, 0.f, 0.f};
  f32x4 acce = (f32x4){0.f, 0.f, 0.f, 0.f};

  for (int j0 = beg; j0 < end; j0 += 64) {
    int nj = end - j0; if (nj > 64) nj = 64;
    int e = 0, s = 0;
    if (lane < nj) { e = edge_list[j0 + lane]; s = src[e]; }
    for (int p = 0; p < nj; p += 4) {
      int i0 = p + slot;
      int i1 = p + 2 + slot;
      int ee0 = __shfl(e, i0), ss0 = __shfl(s, i0);
      int ee1 = __shfl(e, i1), ss1 = __shfl(s, i1);
      bool v0 = i0 < nj, v1 = i1 < nj;
      f32x4 a0, b0, a1, b1;
      if (v0) {
        a0 = nf4[(size_t)ss0 * 32 + c32];
        b0 = __builtin_nontemporal_load(&ef4[(size_t)ee0 * 32 + c32]);
      }
      if (v1) {
        a1 = nf4[(size_t)ss1 * 32 + c32];
        b1 = __builtin_nontemporal_load(&ef4[(size_t)ee1 * 32 + c32]);
      }
      if (v0) { accn += a0; acce += b0; }
      if (v1) { accn += a1; acce += b1; }
    }
  }
  // fold the two half-wave partials
  #pragma unroll
  for (int k = 0; k < 4; ++k) {
    accn[k] += __shfl_xor(accn[k], 32);
    acce[k] += __shfl_xor(acce[k], 32);
  }
  float inv = (cnt > 0) ? 1.0f / (float)cnt : 0.0f;
  f32x4 v = (lane < 32) ? accn : acce;   // lanes 0-31: nf half; 32-63: ef half
  ushort4 o;
  o.x = f2bf(v[0] * inv); o.y = f2bf(v[1] * inv);
  o.z = f2bf(v[2] * inv); o.w = f2bf(v[3] * inv);
  ((ushort4*)(X1 + (size_t)w * TWO_D))[lane] = o;
}

// ---- node kernel: h = X1 @ Wmsg^T + b1*(cnt>0); out = relu(concat(nf,h) @ Wapp^T + b2) ----
// B-fragments come from the packed Wp: each load is a contiguous 1KB wave-load.
__global__ __launch_bounds__(256) void node_gemm(
    const unsigned short* __restrict__ X1,
    const unsigned short* __restrict__ Wp,
    const float* __restrict__ b1,
    const float* __restrict__ b2,
    const float* __restrict__ nfeats,
    const int* __restrict__ offsets,
    float* __restrict__ out,
    int n_nodes) {
  __shared__ unsigned short xt[64 * LDSR];
  __shared__ int cnts[64];
  const int tid = threadIdx.x;
  const int base = blockIdx.x * 64;

  if (tid < 64) {
    int g = base + tid;
    cnts[tid] = (g < n_nodes) ? (offsets[g + 1] - offsets[g]) : 0;
  }
  // stage X1 tile (64 x 256 bf16) into LDS
  #pragma unroll
  for (int it = 0; it < 8; ++it) {
    int chunk = tid + it * 256;          // 2048 chunks of 8 bf16 (16B)
    int r = chunk >> 5, c = chunk & 31;
    int g = base + r;
    uint4 v = make_uint4(0, 0, 0, 0);
    if (g < n_nodes) v = ((const uint4*)X1)[(size_t)g * 32 + c];
    *(uint4*)&xt[r * LDSR + c * 8] = v;
  }
  __syncthreads();

  const int lane = tid & 63;
  const int wid = tid >> 6;
  const int m16 = lane & 15;
  const int quad = lane >> 4;
  const int arow = wid * 16 + m16;
  const int lane8 = lane << 3;

  f32x4 acc[8];
  #pragma unroll
  for (int ot = 0; ot < 8; ++ot) acc[ot] = (f32x4){0.f, 0.f, 0.f, 0.f};

  // GEMM1: h = X1 @ Wmsg^T  (packed B: block g=0)
  #pragma unroll
  for (int k0i = 0; k0i < 8; ++k0i) {
    bf16x8 a = *(const bf16x8*)&xt[arow * LDSR + k0i * 32 + quad * 8];
    #pragma unroll
    for (int ot = 0; ot < 8; ++ot) {
      bf16x8 b = *(const bf16x8*)&Wp[((k0i * 8 + ot) << 9) + lane8];
      acc[ot] = __builtin_amdgcn_mfma_f32_16x16x32_bf16(a, b, acc[ot], 0, 0, 0);
    }
  }
  __syncthreads();  // all waves done reading xt before overwrite

  // write h_neigh (bf16) into xt[:,128:256]; D layout: col=lane&15, row=quad*4+reg
  #pragma unroll
  for (int ot = 0; ot < 8; ++ot) {
    int o = ot * 16 + m16;
    float bias = b1[o];
    #pragma unroll
    for (int r = 0; r < 4; ++r) {
      int m = wid * 16 + quad * 4 + r;
      float h = acc[ot][r] + (cnts[m] > 0 ? bias : 0.0f);
      xt[m * LDSR + 128 + o] = f2bf(h);
    }
  }
  // stage nfeats (bf16) into xt[:,0:128]
  #pragma unroll
  for (int it = 0; it < 8; ++it) {
    int chunk = tid + it * 256;          // 2048 chunks of 4 floats
    int r = chunk >> 5, c = chunk & 31;
    int g = base + r;
    float4 v = make_float4(0.f, 0.f, 0.f, 0.f);
    if (g < n_nodes) v = ((const float4*)nfeats)[(size_t)g * 32 + c];
    ushort4 bv;
    bv.x = f2bf(v.x); bv.y = f2bf(v.y); bv.z = f2bf(v.z); bv.w = f2bf(v.w);
    *(ushort4*)&xt[r * LDSR + c * 4] = bv;
  }
  __syncthreads();

  #pragma unroll
  for (int ot = 0; ot < 8; ++ot) acc[ot] = (f32x4){0.f, 0.f, 0.f, 0.f};

  // GEMM2: out = relu(X2 @ Wapp^T + b2)  (packed B: block g=1 -> +32768 elems)
  #pragma unroll
  for (int k0i = 0; k0i < 8; ++k0i) {
    bf16x8 a = *(const bf16x8*)&xt[arow * LDSR + k0i * 32 + quad * 8];
    #pragma unroll
    for (int ot = 0; ot < 8; ++ot) {
      bf16x8 b = *(const bf16x8*)&Wp[32768 + ((k0i * 8 + ot) << 9) + lane8];
      acc[ot] = __builtin_amdgcn_mfma_f32_16x16x32_bf16(a, b, acc[ot], 0, 0, 0);
    }
  }
  #pragma unroll
  for (int ot = 0; ot < 8; ++ot) {
    int o = ot * 16 + m16;
    float bias = b2[o];
    #pragma unroll
    for (int r = 0; r < 4; ++r) {
      int m = wid * 16 + quad * 4 + r;
      int g = base + m;
      if (g < n_nodes) {
        float v = acc[ot][r] + bias;
        out[(size_t)g * D + o] = v > 0.f ? v : 0.f;
      }
    }
  }
}

extern "C" void kernel_launch(void* const* d_in, const int* in_sizes, int n_in,
                              void* d_out, int out_size, void* d_ws, size_t ws_size,
                              hipStream_t stream) {
  const float* nfeats = (const float*)d_in[0];
  const float* efeats = (const float*)d_in[1];
  const float* Wmsg_f = (const float*)d_in[2];
  const float* b1     = (const float*)d_in[3];
  const float* Wapp_f = (const float*)d_in[4];
  const float* b2     = (const float*)d_in[5];
  const int*   src    = (const int*)d_in[6];
  const int*   dst    = (const int*)d_in[7];
  const int n_nodes = in_sizes[0] / D;
  const int n_edges = in_sizes[6];

  // workspace layout (~29 MB)
  char* ws = (char*)d_ws;
  size_t off = 0;
  unsigned short* X1 = (unsigned short*)(ws + off); off += (size_t)n_nodes * TWO_D * 2;
  unsigned short* Wp = (unsigned short*)(ws + off); off += (size_t)2 * D * TWO_D * 2;
  int* counts    = (int*)(ws + off); off += (size_t)n_nodes * 4;
  int* offsets   = (int*)(ws + off); off += (size_t)(n_nodes + 1) * 4;
  int* cursor    = (int*)(ws + off); off += (size_t)n_nodes * 4;
  int* edge_list = (int*)(ws + off); off += (size_t)n_edges * 4;
  (void)ws_size; (void)n_in; (void)out_size;

  prep_pack<<<256, 256, 0, stream>>>(Wmsg_f, Wapp_f, Wp, counts, n_nodes);
  hist_kernel<<<(n_edges + 255) / 256, 256, 0, stream>>>(dst, counts, n_edges);
  scan_kernel<<<1, 1024, 0, stream>>>(counts, offsets, cursor, n_nodes, n_edges);
  scatter_kernel<<<(n_edges + 255) / 256, 256, 0, stream>>>(dst, cursor, edge_list, n_edges);
  gather_kernel<<<(n_nodes + 3) / 4, 256, 0, stream>>>(nfeats, efeats, src, edge_list, offsets, X1, n_nodes);
  node_gemm<<<(n_nodes + 63) / 64, 256, 0, stream>>>(X1, Wp, b1, b2, nfeats, offsets, (float*)d_out, n_nodes);
}

// Round 5
// 617.917 us; speedup vs baseline: 1.2757x; 1.1156x over previous
//
#include <hip/hip_runtime.h>

#define D 128
#define TWO_D 256
#define LDSR 264   // LDS row stride in bf16 units: 256 + 8 pad

typedef __attribute__((ext_vector_type(4))) float f32x4;
typedef __attribute__((ext_vector_type(8))) short bf16x8;

static __device__ __forceinline__ unsigned short f2bf(float x) {
  union { float f; unsigned u; } v; v.f = x;
  unsigned r = (v.u + 0x7fffu + ((v.u >> 16) & 1u)) >> 16;  // RNE
  return (unsigned short)r;
}

// ---- prep: pack both weights into MFMA-B-fragment order (bf16); zero counts.
// Wp[((g*8+k0i)*8+ot)*512 + lane*8 + j] = W_g[ot*16+(lane&15)][k0i*32+(lane>>4)*8+j]
__global__ void prep_pack(const float* __restrict__ wmsg,
                          const float* __restrict__ wapp,
                          unsigned short* __restrict__ Wp,
                          int* __restrict__ counts, int n_nodes) {
  int p = blockIdx.x * blockDim.x + threadIdx.x;   // 65536 threads
  int j = p & 7;
  int lane = (p >> 3) & 63;
  int ot = (p >> 9) & 7;
  int k0i = (p >> 12) & 7;
  int g = p >> 15;
  int o = ot * 16 + (lane & 15);
  int k = k0i * 32 + (lane >> 4) * 8 + j;
  const float* W = g ? wapp : wmsg;
  Wp[p] = f2bf(W[o * 256 + k]);
  if (p < n_nodes) counts[p] = 0;
}

// ---- hist + rank: the atomic's return value is the edge's rank in its bucket ----
__global__ void hist_rank_kernel(const int* __restrict__ dst, int* __restrict__ counts,
                                 int* __restrict__ rank, int n_edges) {
  int e = blockIdx.x * blockDim.x + threadIdx.x;
  if (e < n_edges) rank[e] = atomicAdd(&counts[dst[e]], 1);
}

// ---- single-block exclusive scan (N=50000) ----
__global__ void scan_kernel(const int* __restrict__ counts, int* __restrict__ offsets,
                            int n, int n_edges) {
  __shared__ int lds[1024];
  int t = threadIdx.x;
  int C = (n + 1023) / 1024;
  int beg = t * C;
  int end = beg + C; if (end > n) end = n;
  int s = 0;
  for (int i = beg; i < end; ++i) s += counts[i];
  lds[t] = s;
  __syncthreads();
  for (int off = 1; off < 1024; off <<= 1) {
    int v = (t >= off) ? lds[t - off] : 0;
    __syncthreads();
    lds[t] += v;
    __syncthreads();
  }
  int run = (t == 0) ? 0 : lds[t - 1];
  for (int i = beg; i < end; ++i) {
    offsets[i] = run;
    run += counts[i];
  }
  if (t == 1023) offsets[n] = n_edges;
}

// ---- scatter (atomic-free): edge_list[offsets[d]+rank[e]] = (e, src[e]) ----
__global__ void scatter_kernel(const int* __restrict__ dst, const int* __restrict__ src,
                               const int* __restrict__ rank,
                               const int* __restrict__ offsets,
                               int2* __restrict__ edge_list, int n_edges) {
  int e = blockIdx.x * blockDim.x + threadIdx.x;
  if (e < n_edges) {
    int d = dst[e];
    edge_list[offsets[d] + rank[e]] = make_int2(e, src[e]);
  }
}

// ---- fused: gather 64-node means into LDS (bf16), then both MFMA GEMMs ----
// Block: 256 threads (4 waves). Wave w gathers nodes w*16..w*16+15 of the tile.
__global__ __launch_bounds__(256) void gcn_fused(
    const float* __restrict__ nfeats, const float* __restrict__ efeats,
    const int2* __restrict__ edge_list, const int* __restrict__ offsets,
    const unsigned short* __restrict__ Wp,
    const float* __restrict__ b1, const float* __restrict__ b2,
    float* __restrict__ out, int n_nodes) {
  __shared__ unsigned short xt[64 * LDSR];
  __shared__ int cnts[64];
  const int tid = threadIdx.x;
  const int base = blockIdx.x * 64;
  const int lane = tid & 63;
  const int wid = tid >> 6;

  const f32x4* nf4 = (const f32x4*)nfeats;   // 32 f32x4 per 512B row
  const f32x4* ef4 = (const f32x4*)efeats;
  const int c32 = lane & 31;
  const int slot = lane >> 5;

  // ---- Phase A: per-wave gather of 16 node-rows into xt ----
  for (int i = 0; i < 16; ++i) {
    int m = wid * 16 + i;
    int g = base + m;
    if (g >= n_nodes) break;           // wave-uniform
    int beg = offsets[g], end = offsets[g + 1];
    int cnt = end - beg;
    f32x4 accn = (f32x4){0.f, 0.f, 0.f, 0.f};
    f32x4 acce = (f32x4){0.f, 0.f, 0.f, 0.f};
    for (int j0 = beg; j0 < end; j0 += 64) {
      int nj = end - j0; if (nj > 64) nj = 64;
      int e = 0, s = 0;
      if (lane < nj) { int2 es = edge_list[j0 + lane]; e = es.x; s = es.y; }
      for (int p = 0; p < nj; p += 4) {
        int i0 = p + slot;
        int i1 = p + 2 + slot;
        int ee0 = __shfl(e, i0), ss0 = __shfl(s, i0);
        int ee1 = __shfl(e, i1), ss1 = __shfl(s, i1);
        bool v0 = i0 < nj, v1 = i1 < nj;
        f32x4 a0, b0, a1, b1v;
        if (v0) {
          a0 = nf4[(size_t)ss0 * 32 + c32];
          b0 = __builtin_nontemporal_load(&ef4[(size_t)ee0 * 32 + c32]);
        }
        if (v1) {
          a1 = nf4[(size_t)ss1 * 32 + c32];
          b1v = __builtin_nontemporal_load(&ef4[(size_t)ee1 * 32 + c32]);
        }
        if (v0) { accn += a0; acce += b0; }
        if (v1) { accn += a1; acce += b1v; }
      }
    }
    #pragma unroll
    for (int k = 0; k < 4; ++k) {
      accn[k] += __shfl_xor(accn[k], 32);
      acce[k] += __shfl_xor(acce[k], 32);
    }
    float inv = (cnt > 0) ? 1.0f / (float)cnt : 0.0f;
    f32x4 v = (lane < 32) ? accn : acce;   // lanes 0-31: nf cols 0..127; 32-63: ef cols 128..255
    ushort4 o;
    o.x = f2bf(v[0] * inv); o.y = f2bf(v[1] * inv);
    o.z = f2bf(v[2] * inv); o.w = f2bf(v[3] * inv);
    *(ushort4*)&xt[m * LDSR + lane * 4] = o;
    if (lane == 0) cnts[m] = cnt;
  }
  __syncthreads();

  const int m16 = lane & 15;
  const int quad = lane >> 4;
  const int arow = wid * 16 + m16;
  const int lane8 = lane << 3;

  f32x4 acc[8];
  #pragma unroll
  for (int ot = 0; ot < 8; ++ot) acc[ot] = (f32x4){0.f, 0.f, 0.f, 0.f};

  // ---- GEMM1: h = X1 @ Wmsg^T (packed B, block g=0) ----
  #pragma unroll
  for (int k0i = 0; k0i < 8; ++k0i) {
    bf16x8 a = *(const bf16x8*)&xt[arow * LDSR + k0i * 32 + quad * 8];
    #pragma unroll
    for (int ot = 0; ot < 8; ++ot) {
      bf16x8 b = *(const bf16x8*)&Wp[((k0i * 8 + ot) << 9) + lane8];
      acc[ot] = __builtin_amdgcn_mfma_f32_16x16x32_bf16(a, b, acc[ot], 0, 0, 0);
    }
  }
  __syncthreads();   // all waves done reading xt before overwrite

  // write h_neigh (bf16) into xt[:,128:256]; C/D layout: col=lane&15, row=quad*4+r
  #pragma unroll
  for (int ot = 0; ot < 8; ++ot) {
    int o = ot * 16 + m16;
    float bias = b1[o];
    #pragma unroll
    for (int r = 0; r < 4; ++r) {
      int m = wid * 16 + quad * 4 + r;
      float h = acc[ot][r] + (cnts[m] > 0 ? bias : 0.0f);
      xt[m * LDSR + 128 + o] = f2bf(h);
    }
  }
  // stage this tile's own nfeats (bf16) into xt[:,0:128]
  #pragma unroll
  for (int it = 0; it < 8; ++it) {
    int chunk = tid + it * 256;          // 2048 chunks of 4 floats
    int r = chunk >> 5, c = chunk & 31;
    int g = base + r;
    float4 v = make_float4(0.f, 0.f, 0.f, 0.f);
    if (g < n_nodes) v = ((const float4*)nfeats)[(size_t)g * 32 + c];
    ushort4 bv;
    bv.x = f2bf(v.x); bv.y = f2bf(v.y); bv.z = f2bf(v.z); bv.w = f2bf(v.w);
    *(ushort4*)&xt[r * LDSR + c * 4] = bv;
  }
  __syncthreads();

  #pragma unroll
  for (int ot = 0; ot < 8; ++ot) acc[ot] = (f32x4){0.f, 0.f, 0.f, 0.f};

  // ---- GEMM2: out = relu(X2 @ Wapp^T + b2) (packed B, block g=1: +32768) ----
  #pragma unroll
  for (int k0i = 0; k0i < 8; ++k0i) {
    bf16x8 a = *(const bf16x8*)&xt[arow * LDSR + k0i * 32 + quad * 8];
    #pragma unroll
    for (int ot = 0; ot < 8; ++ot) {
      bf16x8 b = *(const bf16x8*)&Wp[32768 + ((k0i * 8 + ot) << 9) + lane8];
      acc[ot] = __builtin_amdgcn_mfma_f32_16x16x32_bf16(a, b, acc[ot], 0, 0, 0);
    }
  }
  #pragma unroll
  for (int ot = 0; ot < 8; ++ot) {
    int o = ot * 16 + m16;
    float bias = b2[o];
    #pragma unroll
    for (int r = 0; r < 4; ++r) {
      int m = wid * 16 + quad * 4 + r;
      int g = base + m;
      if (g < n_nodes) {
        float v = acc[ot][r] + bias;
        out[(size_t)g * D + o] = v > 0.f ? v : 0.f;
      }
    }
  }
}

extern "C" void kernel_launch(void* const* d_in, const int* in_sizes, int n_in,
                              void* d_out, int out_size, void* d_ws, size_t ws_size,
                              hipStream_t stream) {
  const float* nfeats = (const float*)d_in[0];
  const float* efeats = (const float*)d_in[1];
  const float* Wmsg_f = (const float*)d_in[2];
  const float* b1     = (const float*)d_in[3];
  const float* Wapp_f = (const float*)d_in[4];
  const float* b2     = (const float*)d_in[5];
  const int*   src    = (const int*)d_in[6];
  const int*   dst    = (const int*)d_in[7];
  const int n_nodes = in_sizes[0] / D;
  const int n_edges = in_sizes[6];

  // workspace layout (~8.5 MB)
  char* ws = (char*)d_ws;
  size_t off = 0;
  unsigned short* Wp = (unsigned short*)(ws + off); off += (size_t)2 * D * TWO_D * 2;
  int* counts    = (int*)(ws + off); off += (size_t)n_nodes * 4;
  int* offsets   = (int*)(ws + off); off += (size_t)(n_nodes + 1) * 4;
  int* rank      = (int*)(ws + off); off += (size_t)n_edges * 4;
  int2* edge_list = (int2*)(ws + off); off += (size_t)n_edges * 8;
  (void)ws_size; (void)n_in; (void)out_size;

  prep_pack<<<256, 256, 0, stream>>>(Wmsg_f, Wapp_f, Wp, counts, n_nodes);
  hist_rank_kernel<<<(n_edges + 255) / 256, 256, 0, stream>>>(dst, counts, rank, n_edges);
  scan_kernel<<<1, 1024, 0, stream>>>(counts, offsets, n_nodes, n_edges);
  scatter_kernel<<<(n_edges + 255) / 256, 256, 0, stream>>>(dst, src, rank, offsets, edge_list, n_edges);
  gcn_fused<<<(n_nodes + 63) / 64, 256, 0, stream>>>(nfeats, efeats, edge_list, offsets, Wp, b1, b2, (float*)d_out, n_nodes);
}

// Round 6
// 555.982 us; speedup vs baseline: 1.4178x; 1.1114x over previous
//
#include <hip/hip_runtime.h>

#define D 128
#define TWO_D 256
#define LDSR 264   // LDS row stride in bf16 units: 256 + 8 pad

typedef __attribute__((ext_vector_type(4))) float f32x4;
typedef __attribute__((ext_vector_type(8))) short bf16x8;

static __device__ __forceinline__ unsigned short f2bf(float x) {
  union { float f; unsigned u; } v; v.f = x;
  unsigned r = (v.u + 0x7fffu + ((v.u >> 16) & 1u)) >> 16;  // RNE
  return (unsigned short)r;
}

// ---- prep: pack both weights into MFMA-B-fragment order (bf16); zero counts.
__global__ void prep_pack(const float* __restrict__ wmsg,
                          const float* __restrict__ wapp,
                          unsigned short* __restrict__ Wp,
                          int* __restrict__ counts, int n_nodes) {
  int p = blockIdx.x * blockDim.x + threadIdx.x;   // 65536 threads
  int j = p & 7;
  int lane = (p >> 3) & 63;
  int ot = (p >> 9) & 7;
  int k0i = (p >> 12) & 7;
  int g = p >> 15;
  int o = ot * 16 + (lane & 15);
  int k = k0i * 32 + (lane >> 4) * 8 + j;
  const float* W = g ? wapp : wmsg;
  Wp[p] = f2bf(W[o * 256 + k]);
  if (p < n_nodes) counts[p] = 0;
}

// ---- hist + rank ----
__global__ void hist_rank_kernel(const int* __restrict__ dst, int* __restrict__ counts,
                                 int* __restrict__ rank, int n_edges) {
  int e = blockIdx.x * blockDim.x + threadIdx.x;
  if (e < n_edges) rank[e] = atomicAdd(&counts[dst[e]], 1);
}

// ---- parallel scan, phase 1: per-block partial sums (1024 elems/block) ----
__global__ void scan_part(const int* __restrict__ counts, int* __restrict__ partial,
                          int n) {
  __shared__ int lds[256];
  int b = blockIdx.x, t = threadIdx.x;
  int g0 = b * 1024 + t * 4;
  int s = 0;
  #pragma unroll
  for (int j = 0; j < 4; ++j) { int g = g0 + j; if (g < n) s += counts[g]; }
  lds[t] = s;
  __syncthreads();
  for (int off = 128; off > 0; off >>= 1) {
    if (t < off) lds[t] += lds[t + off];
    __syncthreads();
  }
  if (t == 0) partial[b] = lds[0];
}

// ---- parallel scan, phase 2: per-block exclusive scan + write offsets ----
__global__ void scan_write(const int* __restrict__ counts, const int* __restrict__ partial,
                           int* __restrict__ offsets, int n, int n_edges, int nb) {
  __shared__ int lds[256];
  __shared__ int pb[64];
  int b = blockIdx.x, t = threadIdx.x;
  if (t < nb) pb[t] = partial[t];
  __syncthreads();
  int base = 0;
  for (int k = 0; k < b; ++k) base += pb[k];
  int g0 = b * 1024 + t * 4;
  int c0 = (g0 + 0 < n) ? counts[g0 + 0] : 0;
  int c1 = (g0 + 1 < n) ? counts[g0 + 1] : 0;
  int c2 = (g0 + 2 < n) ? counts[g0 + 2] : 0;
  int c3 = (g0 + 3 < n) ? counts[g0 + 3] : 0;
  lds[t] = c0 + c1 + c2 + c3;
  __syncthreads();
  for (int off = 1; off < 256; off <<= 1) {
    int v = (t >= off) ? lds[t - off] : 0;
    __syncthreads();
    lds[t] += v;
    __syncthreads();
  }
  int texc = base + ((t > 0) ? lds[t - 1] : 0);
  if (g0 + 0 < n) offsets[g0 + 0] = texc;
  if (g0 + 1 < n) offsets[g0 + 1] = texc + c0;
  if (g0 + 2 < n) offsets[g0 + 2] = texc + c0 + c1;
  if (g0 + 3 < n) offsets[g0 + 3] = texc + c0 + c1 + c2;
  if (b == 0 && t == 0) offsets[n] = n_edges;
}

// ---- scatter (atomic-free): edge_list[offsets[d]+rank[e]] = (e, src[e]) ----
__global__ void scatter_kernel(const int* __restrict__ dst, const int* __restrict__ src,
                               const int* __restrict__ rank,
                               const int* __restrict__ offsets,
                               int2* __restrict__ edge_list, int n_edges) {
  int e = blockIdx.x * blockDim.x + threadIdx.x;
  if (e < n_edges) {
    int d = dst[e];
    edge_list[offsets[d] + rank[e]] = make_int2(e, src[e]);
  }
}

// ---- gather v4: one wave per node; batched ids + shfl; software-pipelined
// (prefetch next 4-edge group's row loads before consuming current group). ----
__global__ __launch_bounds__(256) void gather_kernel(
    const float* __restrict__ nfeats, const float* __restrict__ efeats,
    const int2* __restrict__ edge_list, const int* __restrict__ offsets,
    unsigned short* __restrict__ X1, int n_nodes) {
  int w = (blockIdx.x * 256 + threadIdx.x) >> 6;
  int lane = threadIdx.x & 63;
  if (w >= n_nodes) return;
  int beg = offsets[w], end = offsets[w + 1];
  int cnt = end - beg;
  const f32x4* nf4 = (const f32x4*)nfeats;
  const f32x4* ef4 = (const f32x4*)efeats;
  const int c32 = lane & 31;
  const int slot = lane >> 5;
  f32x4 accn = (f32x4){0.f, 0.f, 0.f, 0.f};
  f32x4 acce = (f32x4){0.f, 0.f, 0.f, 0.f};

  for (int j0 = beg; j0 < end; j0 += 64) {
    int nj = end - j0; if (nj > 64) nj = 64;
    int e = 0, s = 0;
    if (lane < nj) { int2 es = edge_list[j0 + lane]; e = es.x; s = es.y; }
    // prologue: issue group 0 (edges slot, 2+slot)
    int i0 = slot, i1 = 2 + slot;
    int ee0 = __shfl(e, i0), ss0 = __shfl(s, i0);
    int ee1 = __shfl(e, i1), ss1 = __shfl(s, i1);
    bool v0 = i0 < nj, v1 = i1 < nj;
    f32x4 a0 = (f32x4){0.f,0.f,0.f,0.f}, b0 = a0, a1 = a0, b1v = a0;
    if (v0) { a0 = nf4[(size_t)ss0 * 32 + c32];
              b0 = __builtin_nontemporal_load(&ef4[(size_t)ee0 * 32 + c32]); }
    if (v1) { a1 = nf4[(size_t)ss1 * 32 + c32];
              b1v = __builtin_nontemporal_load(&ef4[(size_t)ee1 * 32 + c32]); }
    for (int p = 0; p < nj; p += 4) {
      // issue next group before consuming current
      int n0 = (p + 4 + slot) & 63, n1 = (p + 6 + slot) & 63;
      int eeN0 = __shfl(e, n0), ssN0 = __shfl(s, n0);
      int eeN1 = __shfl(e, n1), ssN1 = __shfl(s, n1);
      bool w0 = p + 4 + slot < nj, w1 = p + 6 + slot < nj;
      f32x4 aN0 = (f32x4){0.f,0.f,0.f,0.f}, bN0 = aN0, aN1 = aN0, bN1 = aN0;
      if (w0) { aN0 = nf4[(size_t)ssN0 * 32 + c32];
                bN0 = __builtin_nontemporal_load(&ef4[(size_t)eeN0 * 32 + c32]); }
      if (w1) { aN1 = nf4[(size_t)ssN1 * 32 + c32];
                bN1 = __builtin_nontemporal_load(&ef4[(size_t)eeN1 * 32 + c32]); }
      // consume current
      if (v0) { accn += a0; acce += b0; }
      if (v1) { accn += a1; acce += b1v; }
      a0 = aN0; b0 = bN0; a1 = aN1; b1v = bN1; v0 = w0; v1 = w1;
    }
  }
  #pragma unroll
  for (int k = 0; k < 4; ++k) {
    accn[k] += __shfl_xor(accn[k], 32);
    acce[k] += __shfl_xor(acce[k], 32);
  }
  float inv = (cnt > 0) ? 1.0f / (float)cnt : 0.0f;
  f32x4 v = (lane < 32) ? accn : acce;   // lanes 0-31: nf cols; 32-63: ef cols
  ushort4 o;
  o.x = f2bf(v[0] * inv); o.y = f2bf(v[1] * inv);
  o.z = f2bf(v[2] * inv); o.w = f2bf(v[3] * inv);
  ((ushort4*)(X1 + (size_t)w * TWO_D))[lane] = o;
}

// ---- node kernel (R4 structure): packed-B MFMA GEMMs over X1 ----
__global__ __launch_bounds__(256) void node_gemm(
    const unsigned short* __restrict__ X1,
    const unsigned short* __restrict__ Wp,
    const float* __restrict__ b1,
    const float* __restrict__ b2,
    const float* __restrict__ nfeats,
    const int* __restrict__ offsets,
    float* __restrict__ out,
    int n_nodes) {
  __shared__ unsigned short xt[64 * LDSR];
  __shared__ int cnts[64];
  const int tid = threadIdx.x;
  const int base = blockIdx.x * 64;

  if (tid < 64) {
    int g = base + tid;
    cnts[tid] = (g < n_nodes) ? (offsets[g + 1] - offsets[g]) : 0;
  }
  #pragma unroll
  for (int it = 0; it < 8; ++it) {
    int chunk = tid + it * 256;
    int r = chunk >> 5, c = chunk & 31;
    int g = base + r;
    uint4 v = make_uint4(0, 0, 0, 0);
    if (g < n_nodes) v = ((const uint4*)X1)[(size_t)g * 32 + c];
    *(uint4*)&xt[r * LDSR + c * 8] = v;
  }
  __syncthreads();

  const int lane = tid & 63;
  const int wid = tid >> 6;
  const int m16 = lane & 15;
  const int quad = lane >> 4;
  const int arow = wid * 16 + m16;
  const int lane8 = lane << 3;

  f32x4 acc[8];
  #pragma unroll
  for (int ot = 0; ot < 8; ++ot) acc[ot] = (f32x4){0.f, 0.f, 0.f, 0.f};

  #pragma unroll
  for (int k0i = 0; k0i < 8; ++k0i) {
    bf16x8 a = *(const bf16x8*)&xt[arow * LDSR + k0i * 32 + quad * 8];
    #pragma unroll
    for (int ot = 0; ot < 8; ++ot) {
      bf16x8 b = *(const bf16x8*)&Wp[((k0i * 8 + ot) << 9) + lane8];
      acc[ot] = __builtin_amdgcn_mfma_f32_16x16x32_bf16(a, b, acc[ot], 0, 0, 0);
    }
  }
  __syncthreads();

  #pragma unroll
  for (int ot = 0; ot < 8; ++ot) {
    int o = ot * 16 + m16;
    float bias = b1[o];
    #pragma unroll
    for (int r = 0; r < 4; ++r) {
      int m = wid * 16 + quad * 4 + r;
      float h = acc[ot][r] + (cnts[m] > 0 ? bias : 0.0f);
      xt[m * LDSR + 128 + o] = f2bf(h);
    }
  }
  #pragma unroll
  for (int it = 0; it < 8; ++it) {
    int chunk = tid + it * 256;
    int r = chunk >> 5, c = chunk & 31;
    int g = base + r;
    float4 v = make_float4(0.f, 0.f, 0.f, 0.f);
    if (g < n_nodes) v = ((const float4*)nfeats)[(size_t)g * 32 + c];
    ushort4 bv;
    bv.x = f2bf(v.x); bv.y = f2bf(v.y); bv.z = f2bf(v.z); bv.w = f2bf(v.w);
    *(ushort4*)&xt[r * LDSR + c * 4] = bv;
  }
  __syncthreads();

  #pragma unroll
  for (int ot = 0; ot < 8; ++ot) acc[ot] = (f32x4){0.f, 0.f, 0.f, 0.f};

  #pragma unroll
  for (int k0i = 0; k0i < 8; ++k0i) {
    bf16x8 a = *(const bf16x8*)&xt[arow * LDSR + k0i * 32 + quad * 8];
    #pragma unroll
    for (int ot = 0; ot < 8; ++ot) {
      bf16x8 b = *(const bf16x8*)&Wp[32768 + ((k0i * 8 + ot) << 9) + lane8];
      acc[ot] = __builtin_amdgcn_mfma_f32_16x16x32_bf16(a, b, acc[ot], 0, 0, 0);
    }
  }
  #pragma unroll
  for (int ot = 0; ot < 8; ++ot) {
    int o = ot * 16 + m16;
    float bias = b2[o];
    #pragma unroll
    for (int r = 0; r < 4; ++r) {
      int m = wid * 16 + quad * 4 + r;
      int g = base + m;
      if (g < n_nodes) {
        float v = acc[ot][r] + bias;
        out[(size_t)g * D + o] = v > 0.f ? v : 0.f;
      }
    }
  }
}

extern "C" void kernel_launch(void* const* d_in, const int* in_sizes, int n_in,
                              void* d_out, int out_size, void* d_ws, size_t ws_size,
                              hipStream_t stream) {
  const float* nfeats = (const float*)d_in[0];
  const float* efeats = (const float*)d_in[1];
  const float* Wmsg_f = (const float*)d_in[2];
  const float* b1     = (const float*)d_in[3];
  const float* Wapp_f = (const float*)d_in[4];
  const float* b2     = (const float*)d_in[5];
  const int*   src    = (const int*)d_in[6];
  const int*   dst    = (const int*)d_in[7];
  const int n_nodes = in_sizes[0] / D;
  const int n_edges = in_sizes[6];
  const int nb = (n_nodes + 1023) / 1024;   // scan blocks (49)

  char* ws = (char*)d_ws;
  size_t off = 0;
  unsigned short* X1 = (unsigned short*)(ws + off); off += (size_t)n_nodes * TWO_D * 2;
  unsigned short* Wp = (unsigned short*)(ws + off); off += (size_t)2 * D * TWO_D * 2;
  int* counts    = (int*)(ws + off); off += (size_t)n_nodes * 4;
  int* offsets   = (int*)(ws + off); off += (size_t)(n_nodes + 1) * 4;
  int* rank      = (int*)(ws + off); off += (size_t)n_edges * 4;
  int* partial   = (int*)(ws + off); off += 64 * 4;
  int2* edge_list = (int2*)(ws + off); off += (size_t)n_edges * 8;
  (void)ws_size; (void)n_in; (void)out_size;

  prep_pack<<<256, 256, 0, stream>>>(Wmsg_f, Wapp_f, Wp, counts, n_nodes);
  hist_rank_kernel<<<(n_edges + 255) / 256, 256, 0, stream>>>(dst, counts, rank, n_edges);
  scan_part<<<nb, 256, 0, stream>>>(counts, partial, n_nodes);
  scan_write<<<nb, 256, 0, stream>>>(counts, partial, offsets, n_nodes, n_edges, nb);
  scatter_kernel<<<(n_edges + 255) / 256, 256, 0, stream>>>(dst, src, rank, offsets, edge_list, n_edges);
  gather_kernel<<<(n_nodes + 3) / 4, 256, 0, stream>>>(nfeats, efeats, edge_list, offsets, X1, n_nodes);
  node_gemm<<<(n_nodes + 63) / 64, 256, 0, stream>>>(X1, Wp, b1, b2, nfeats, offsets, (float*)d_out, n_nodes);
}